// Round 2
// baseline (200.646 us; speedup 1.0000x reference)
//
#include <hip/hip_runtime.h>

#define HH 128
#define WW 128
#define CC 96
#define KK 7

// LDS-staged morphological dilation (7x7 max-plus, zero-pad, ReLU folded).
// Block: 256 threads, one (b,c) plane half: 64 out rows x 128 cols.
// Stage 70 rows (64 + 6 halo) x 136 cols (128 + 4+4 col pad, zeros baked in)
// into LDS (38080 B), one barrier, then compute entirely from LDS with
// compile-time ds_read offsets: no bounds checks, no cndmasks, no 64-bit
// address arithmetic in the hot loop.
//
// Thread t: cg = t&31 -> out cols [4*cg, 4*cg+4); rg = t>>5 -> out rows
// [half*64 + 8*rg, +8). Streaming accumulator: input rows consumed top-down,
// each feeds <=7 pending output rows; weight row i = s - yl folds statically.

#define LROWS 70
#define LW 136                    // floats per LDS row; col c at index c+4
#define LSLOTS (LROWS * (LW / 4)) // 2380 float4 slots

__global__ __launch_bounds__(256) void morph_kernel(
    const float* __restrict__ x, const float* __restrict__ weight,
    float* __restrict__ out) {
  __shared__ float lds[LROWS * LW];  // 38080 B

  const int t = threadIdx.x;
  const int half = blockIdx.x & 1;
  const int plane = blockIdx.x >> 1;  // b*CC + c
  const int c = plane % CC;

  const float* __restrict__ xp = x + (size_t)plane * (HH * WW);
  float* __restrict__ op = out + (size_t)plane * (HH * WW);
  const float* __restrict__ Wc = weight + c * (KK * KK);

  // Preload 49 channel weights; force into SGPRs (block-uniform).
  float wv[KK * KK];
#pragma unroll
  for (int k = 0; k < KK * KK; ++k)
    wv[k] = __int_as_float(__builtin_amdgcn_readfirstlane(__float_as_int(Wc[k])));

  // ---- Stage half-plane + halo into LDS (zeros for all padding). ----
  const int r0g = half * 64 - 3;  // global row of LDS row 0
#pragma unroll
  for (int k = 0; k < (LSLOTS + 255) / 256; ++k) {
    const unsigned idx = k * 256 + t;
    if (idx < LSLOTS) {
      const unsigned row = idx / 34;         // magic-mul division
      const unsigned c4 = idx - row * 34;    // float4 slot within row
      const int gr = r0g + (int)row;
      float4 v = make_float4(0.f, 0.f, 0.f, 0.f);
      // c4==0 -> cols -4..-1 (pad), c4==33 -> cols 128..131 (pad)
      if ((unsigned)gr < (unsigned)HH && c4 >= 1 && c4 <= 32) {
        v = *(const float4*)(xp + gr * WW + (c4 - 1) * 4);
      }
      *(float4*)(&lds[row * LW + c4 * 4]) = v;
    }
  }
  __syncthreads();

  // ---- Compute from LDS. ----
  const int cg = t & 31;
  const int rg = t >> 5;
  const int tc0 = cg << 2;               // first out col
  const int row0 = half * 64 + rg * 8;   // first out row
  // LDS pointer at (LDS row rg*8, LDS col index tc0) = actual col tc0-4.
  const float* __restrict__ lp = &lds[(rg * 8) * LW + tc0];

  float acc[8][4];
#pragma unroll
  for (int y = 0; y < 8; ++y)
#pragma unroll
    for (int q = 0; q < 4; ++q) acc[y][q] = 0.f;  // ReLU: start at 0

#pragma unroll
  for (int s = 0; s < 14; ++s) {
    // 12-float strip, cols [tc0-4, tc0+8): three b128 reads, imm offsets.
    float d[12];
    {
      const float4 A = *(const float4*)(lp + s * LW);
      const float4 B = *(const float4*)(lp + s * LW + 4);
      const float4 C = *(const float4*)(lp + s * LW + 8);
      d[0] = A.x; d[1] = A.y; d[2] = A.z; d[3] = A.w;
      d[4] = B.x; d[5] = B.y; d[6] = B.z; d[7] = B.w;
      d[8] = C.x; d[9] = C.y; d[10] = C.z; d[11] = C.w;
    }

#pragma unroll
    for (int yl = 0; yl < 8; ++yl) {
      const int i = s - yl;            // weight row; folds at compile time
      if (i < 0 || i >= KK) continue;  // static guard (full unroll)
      const float w0 = wv[i * 7 + 0], w1 = wv[i * 7 + 1], w2 = wv[i * 7 + 2],
                  w3 = wv[i * 7 + 3], w4 = wv[i * 7 + 4], w5 = wv[i * 7 + 5],
                  w6 = wv[i * 7 + 6];
#pragma unroll
      for (int q = 0; q < 4; ++q) {
        const float t0 = d[q + 1] + w0;
        const float t1 = d[q + 2] + w1;
        const float t2 = d[q + 3] + w2;
        const float t3 = d[q + 4] + w3;
        const float t4 = d[q + 5] + w4;
        const float t5 = d[q + 6] + w5;
        const float t6 = d[q + 7] + w6;
        float m = acc[yl][q];
        m = fmaxf(fmaxf(m, t0), t1);   // -> v_max3_f32
        m = fmaxf(fmaxf(m, t2), t3);
        m = fmaxf(fmaxf(m, t4), t5);
        m = fmaxf(m, t6);
        acc[yl][q] = m;
      }
    }

    // Output row row0 + s - 6 complete.
    if (s >= 6) {
      const int yl = s - 6;
      float4 o = make_float4(acc[yl][0], acc[yl][1], acc[yl][2], acc[yl][3]);
      *(float4*)(op + (size_t)(row0 + yl) * WW + tc0) = o;
    }
  }
}

extern "C" void kernel_launch(void* const* d_in, const int* in_sizes, int n_in,
                              void* d_out, int out_size, void* d_ws, size_t ws_size,
                              hipStream_t stream) {
  const float* x = (const float*)d_in[0];
  const float* w = (const float*)d_in[1];
  float* out = (float*)d_out;
  // 16 batches * 96 channels * 2 half-planes
  const int nblocks = 16 * CC * 2;
  morph_kernel<<<nblocks, 256, 0, stream>>>(x, w, out);
}

// Round 3
// 195.889 us; speedup vs baseline: 1.0243x; 1.0243x over previous
//
#include <hip/hip_runtime.h>

#define HH 128
#define WW 128
#define CC 96
#define KK 7

// Direct-global streaming morphological dilation (7x7 max-plus, zero-pad,
// ReLU folded). TLP-doubled vs prior round: one block = one (b,c) plane
// QUARTER (32 rows x 128 cols), 6144 blocks / 24576 waves total, so ~2x the
// waves in flight to hide global-load latency (the measured bottleneck:
// constant ~52us VALU-busy across variants, ~35% occupancy, 30-40% stall).
//
// Thread t: cg = t&31 -> out cols [4*cg, +4); rg = t>>5 -> out rows
// [q0 + 4*rg, +4). Streaming accumulator: 10 input rows consumed top-down,
// each feeds <=7 of the 4 pending output rows; weight row i = s - yl folds
// statically under full unroll. Max reduction is a depth-3 max3 tree.

__device__ __forceinline__ void load_row(float* d, const float* __restrict__ xp,
                                         int r, int tc0, bool lok, bool rok) {
  if ((unsigned)r < (unsigned)HH) {
    const float* p = xp + r * WW + tc0 - 4;
    float4 a, b, c;
    if (lok) a = *(const float4*)(p);
    else     a = make_float4(0.f, 0.f, 0.f, 0.f);
    b = *(const float4*)(p + 4);
    if (rok) c = *(const float4*)(p + 8);
    else     c = make_float4(0.f, 0.f, 0.f, 0.f);
    d[0] = a.x; d[1] = a.y; d[2] = a.z; d[3] = a.w;
    d[4] = b.x; d[5] = b.y; d[6] = b.z; d[7] = b.w;
    d[8] = c.x; d[9] = c.y; d[10] = c.z; d[11] = c.w;
  } else {
#pragma unroll
    for (int i = 0; i < 12; ++i) d[i] = 0.f;
  }
}

__global__ __launch_bounds__(256) void morph_kernel(
    const float* __restrict__ x, const float* __restrict__ weight,
    float* __restrict__ out) {
  const int t = threadIdx.x;
  const int cg = t & 31;   // col group 0..31
  const int rg = t >> 5;   // row group 0..7
  const int quarter = blockIdx.x & 3;
  const int plane = blockIdx.x >> 2;  // b*CC + c
  const int c = plane % CC;

  const float* __restrict__ xp = x + (size_t)plane * (HH * WW);
  float* __restrict__ op = out + (size_t)plane * (HH * WW);
  const float* __restrict__ Wc = weight + c * (KK * KK);

  // Preload 49 channel weights; force into SGPRs (block-uniform).
  float wv[KK * KK];
#pragma unroll
  for (int k = 0; k < KK * KK; ++k)
    wv[k] = __int_as_float(__builtin_amdgcn_readfirstlane(__float_as_int(Wc[k])));

  const int tc0 = cg << 2;                    // first out col of this thread
  const int row0 = quarter * 32 + rg * 4;     // first out row of this thread
  const bool lok = (tc0 >= 4);
  const bool rok = (tc0 <= WW - 8);

  // Pending output accumulators. ReLU folded in: start at 0 (= max(0, .)).
  float acc[4][4];
#pragma unroll
  for (int y = 0; y < 4; ++y)
#pragma unroll
    for (int q = 0; q < 4; ++q) acc[y][q] = 0.f;

  // Stream input rows row0-3 .. row0+6 (10 rows for 4 output rows).
#pragma unroll
  for (int s = 0; s < 10; ++s) {
    float d[12];  // cols [tc0-4, tc0+8); used: d[1..10]
    load_row(d, xp, row0 - 3 + s, tc0, lok, rok);

#pragma unroll
    for (int yl = 0; yl < 4; ++yl) {
      const int i = s - yl;            // weight row; folds at compile time
      if (i < 0 || i >= KK) continue;  // static guard (full unroll)
      const float w0 = wv[i * 7 + 0], w1 = wv[i * 7 + 1], w2 = wv[i * 7 + 2],
                  w3 = wv[i * 7 + 3], w4 = wv[i * 7 + 4], w5 = wv[i * 7 + 5],
                  w6 = wv[i * 7 + 6];
#pragma unroll
      for (int q = 0; q < 4; ++q) {
        const float t0 = d[q + 1] + w0;
        const float t1 = d[q + 2] + w1;
        const float t2 = d[q + 3] + w2;
        const float t3 = d[q + 4] + w3;
        const float t4 = d[q + 5] + w4;
        const float t5 = d[q + 6] + w5;
        const float t6 = d[q + 7] + w6;
        // Depth-3 max3 tree (selects to v_max3_f32), then fold into acc.
        const float u = fmaxf(fmaxf(t0, t1), t2);
        const float v = fmaxf(fmaxf(t3, t4), t5);
        const float m = fmaxf(fmaxf(u, v), t6);
        acc[yl][q] = fmaxf(acc[yl][q], m);
      }
    }

    // Output row (row0 + s - 6) got its last contribution this iteration.
    if (s >= 6) {
      const int yl = s - 6;
      float4 o = make_float4(acc[yl][0], acc[yl][1], acc[yl][2], acc[yl][3]);
      *(float4*)(op + (size_t)(row0 + yl) * WW + tc0) = o;
    }
  }
}

extern "C" void kernel_launch(void* const* d_in, const int* in_sizes, int n_in,
                              void* d_out, int out_size, void* d_ws, size_t ws_size,
                              hipStream_t stream) {
  const float* x = (const float*)d_in[0];
  const float* w = (const float*)d_in[1];
  float* out = (float*)d_out;
  // 16 batches * 96 channels * 4 quarter-planes
  const int nblocks = 16 * CC * 4;
  morph_kernel<<<nblocks, 256, 0, stream>>>(x, w, out);
}

// Round 4
// 195.123 us; speedup vs baseline: 1.0283x; 1.0039x over previous
//
#include <hip/hip_runtime.h>

#define HH 128
#define WW 128
#define CC 96
#define KK 7

// Streaming-accumulator morphological dilation (7x7 max-plus, zero-pad, ReLU
// folded), with explicit v_max3_f32 reduction. The compiler will NOT fuse
// fmaxf chains into v_max3_f32 without NaN-freedom proof, so we emit it via
// inline asm: 4 max ops per 7-tap group instead of 7, cutting core VALU
// issue ~21% (the measured bottleneck: constant ~52us VALU-busy across all
// structural variants).
//
// Block: 256 threads = 32 col-groups x 8 row-groups; one (b,c) plane half
// (64 rows x 128 cols). Thread: 4 cols, 8 output rows, streaming input rows
// top-down (14 rows), each row feeding <=7 pending output accumulators;
// weight row i = s - yl folds statically under full unroll.

__device__ __forceinline__ float max3f(float a, float b, float c) {
  float r;
  asm("v_max3_f32 %0, %1, %2, %3" : "=v"(r) : "v"(a), "v"(b), "v"(c));
  return r;
}

__device__ __forceinline__ void load_row(float* d, const float* __restrict__ xp,
                                         int r, int tc0, bool lok, bool rok) {
  if ((unsigned)r < (unsigned)HH) {
    const float* p = xp + r * WW + tc0 - 4;
    float4 a, b, c;
    if (lok) a = *(const float4*)(p);
    else     a = make_float4(0.f, 0.f, 0.f, 0.f);
    b = *(const float4*)(p + 4);
    if (rok) c = *(const float4*)(p + 8);
    else     c = make_float4(0.f, 0.f, 0.f, 0.f);
    d[0] = a.x; d[1] = a.y; d[2] = a.z; d[3] = a.w;
    d[4] = b.x; d[5] = b.y; d[6] = b.z; d[7] = b.w;
    d[8] = c.x; d[9] = c.y; d[10] = c.z; d[11] = c.w;
  } else {
#pragma unroll
    for (int i = 0; i < 12; ++i) d[i] = 0.f;
  }
}

__global__ __launch_bounds__(256) void morph_kernel(
    const float* __restrict__ x, const float* __restrict__ weight,
    float* __restrict__ out) {
  const int t = threadIdx.x;
  const int cg = t & 31;   // col group 0..31
  const int rg = t >> 5;   // row group 0..7
  const int half = blockIdx.x & 1;
  const int plane = blockIdx.x >> 1;  // b*CC + c
  const int c = plane % CC;

  const float* __restrict__ xp = x + (size_t)plane * (HH * WW);
  float* __restrict__ op = out + (size_t)plane * (HH * WW);
  const float* __restrict__ Wc = weight + c * (KK * KK);

  // Preload 49 channel weights; force into SGPRs (block-uniform).
  float wv[KK * KK];
#pragma unroll
  for (int k = 0; k < KK * KK; ++k)
    wv[k] = __int_as_float(__builtin_amdgcn_readfirstlane(__float_as_int(Wc[k])));

  const int tc0 = cg << 2;              // first out col of this thread
  const int row0 = half * 64 + rg * 8;  // first out row of this thread
  const bool lok = (tc0 >= 4);
  const bool rok = (tc0 <= WW - 8);

  // Pending output accumulators. ReLU folded in: start at 0 (= max(0, .)).
  float acc[8][4];
#pragma unroll
  for (int y = 0; y < 8; ++y)
#pragma unroll
    for (int q = 0; q < 4; ++q) acc[y][q] = 0.f;

  // Stream input rows row0-3 .. row0+10 (14 rows for 8 output rows).
#pragma unroll
  for (int s = 0; s < 14; ++s) {
    float d[12];  // cols [tc0-4, tc0+8); used: d[1..10]
    load_row(d, xp, row0 - 3 + s, tc0, lok, rok);

#pragma unroll
    for (int yl = 0; yl < 8; ++yl) {
      const int i = s - yl;            // weight row; folds at compile time
      if (i < 0 || i >= KK) continue;  // static guard (full unroll)
      const float w0 = wv[i * 7 + 0], w1 = wv[i * 7 + 1], w2 = wv[i * 7 + 2],
                  w3 = wv[i * 7 + 3], w4 = wv[i * 7 + 4], w5 = wv[i * 7 + 5],
                  w6 = wv[i * 7 + 6];
#pragma unroll
      for (int q = 0; q < 4; ++q) {
        const float t0 = d[q + 1] + w0;
        const float t1 = d[q + 2] + w1;
        const float t2 = d[q + 3] + w2;
        const float t3 = d[q + 4] + w3;
        const float t4 = d[q + 5] + w4;
        const float t5 = d[q + 6] + w5;
        const float t6 = d[q + 7] + w6;
        // Depth-3 explicit max3 tree: 3x v_max3_f32 + 1x v_max_f32.
        const float u = max3f(t0, t1, t2);
        const float v = max3f(t3, t4, t5);
        const float m = max3f(u, v, t6);
        acc[yl][q] = fmaxf(acc[yl][q], m);
      }
    }

    // Output row (row0 + s - 6) got its last contribution this iteration.
    if (s >= 6) {
      const int yl = s - 6;
      float4 o = make_float4(acc[yl][0], acc[yl][1], acc[yl][2], acc[yl][3]);
      *(float4*)(op + (size_t)(row0 + yl) * WW + tc0) = o;
    }
  }
}

extern "C" void kernel_launch(void* const* d_in, const int* in_sizes, int n_in,
                              void* d_out, int out_size, void* d_ws, size_t ws_size,
                              hipStream_t stream) {
  const float* x = (const float*)d_in[0];
  const float* w = (const float*)d_in[1];
  float* out = (float*)d_out;
  // 16 batches * 96 channels * 2 half-planes
  const int nblocks = 16 * CC * 2;
  morph_kernel<<<nblocks, 256, 0, stream>>>(x, w, out);
}